// Round 3
// baseline (3812.924 us; speedup 1.0000x reference)
//
#include <hip/hip_runtime.h>
#include <hip/hip_bf16.h>

#define NSWEEP_X 8
#define NSWEEP_W 12

__device__ __forceinline__ void wavefence() {
    __builtin_amdgcn_wave_barrier();
    asm volatile("" ::: "memory");
}

// One-sided Jacobi on a 32x32 matrix held in registers across one wave.
// lane (j = lane&31, b = lane>>5) holds rows b*16..b*16+15 of column j in a[16].
// XOR ordering: masks m=1..31 (compile-time -> ds_swizzle). Column norms^2 are
// maintained incrementally (app' = app - t*apq / aqq' = aqq + t*apq) and
// refreshed once per sweep. After convergence column j = u_j * sigma_j.
__device__ __forceinline__ void jacobi_reg(float a[16], int j, int nsweep) {
    for (int sw = 0; sw < nsweep; ++sw) {
        // exact norm refresh (once per sweep)
        float n0 = 0.f, n1 = 0.f, n2 = 0.f, n3 = 0.f;
#pragma unroll
        for (int i = 0; i < 16; i += 4) {
            n0 = fmaf(a[i+0], a[i+0], n0);
            n1 = fmaf(a[i+1], a[i+1], n1);
            n2 = fmaf(a[i+2], a[i+2], n2);
            n3 = fmaf(a[i+3], a[i+3], n3);
        }
        float nn = (n0 + n1) + (n2 + n3);
        nn += __shfl_xor(nn, 32);

#pragma unroll
        for (int m = 1; m < 32; ++m) {
            float prt[16];
#pragma unroll
            for (int i = 0; i < 16; i++) prt[i] = __shfl_xor(a[i], m);
            float c0 = 0.f, c1 = 0.f, c2 = 0.f, c3 = 0.f;
#pragma unroll
            for (int i = 0; i < 16; i += 4) {
                c0 = fmaf(a[i+0], prt[i+0], c0);
                c1 = fmaf(a[i+1], prt[i+1], c1);
                c2 = fmaf(a[i+2], prt[i+2], c2);
                c3 = fmaf(a[i+3], prt[i+3], c3);
            }
            float cp = (c0 + c1) + (c2 + c3);
            cp += __shfl_xor(cp, 32);          // full dot(own, partner)
            float on = __shfl_xor(nn, m);      // partner column norm^2
            bool isp = j < (j ^ m);
            float app = isp ? nn : on;
            float aqq = isp ? on : nn;
            if (cp * cp > 1e-14f * app * aqq) {
                float tau = (aqq - app) * __builtin_amdgcn_rcpf(2.0f * cp);
                float den = fabsf(tau) + __builtin_amdgcn_sqrtf(fmaf(tau, tau, 1.0f));
                float tt  = copysignf(__builtin_amdgcn_rcpf(den), tau);
                float cth = __builtin_amdgcn_rsqf(fmaf(tt, tt, 1.0f));
                float tsgn = isp ? -tt : tt;   // p-side: -t ; q-side: +t
                float ss   = tsgn * cth;
#pragma unroll
                for (int i = 0; i < 16; i++) a[i] = fmaf(ss, prt[i], cth * a[i]);
                nn = fmaxf(fmaf(tsgn, cp, nn), 0.0f);   // norm^2 update
            }
        }
    }
}

// Rank columns by sigma^2 descending (tie-break by index). Columns with rank<8
// are packed into P0S[rk*33 + h] (h = row), their sigma^2 into sig2S[rk].
__device__ __forceinline__ void rank_and_pack(const float a[16], int j, int b,
                                              float* nrmS, float* P0S, float* sig2S) {
    float nn = 0.f;
#pragma unroll
    for (int i = 0; i < 16; i++) nn = fmaf(a[i], a[i], nn);
    nn += __shfl_xor(nn, 32);
    if (b == 0) nrmS[j] = nn;
    wavefence();
    int rk = 0;
    for (int k = 0; k < 32; k++) {
        float o = nrmS[k];
        rk += (o > nn) || (o == nn && k < j);
    }
    if (rk < 8) {
#pragma unroll
        for (int i = 0; i < 16; i++) P0S[rk * 33 + b * 16 + i] = a[i];
        if (b == 0) sig2S[rk] = nn;
    }
    wavefence();
}

// ---- Kernel 1: SVD of w[c] (32 matrices, one wave per block).
//   uwd[c][h][m] = Uw[h][m]*dw[m]   (converged column)
//   vwt[c][w][m] = Vwh[m][w]        (recovered as A0^T a_m / sigma_m^2)
__global__ __launch_bounds__(64)
void svd_w_kernel(const float* __restrict__ w, float* __restrict__ uwd,
                  float* __restrict__ vwt) {
    __shared__ float P0S[8 * 33];
    __shared__ float nrmS[32];
    __shared__ float sig2S[8];
    const int lane = threadIdx.x, j = lane & 31, b = lane >> 5;
    const int c = blockIdx.x;

    float a[16], a0[16];
#pragma unroll
    for (int i = 0; i < 16; i++) {
        a[i] = w[c * 1024 + (b * 16 + i) * 32 + j];
        a0[i] = a[i];
    }
    jacobi_reg(a, j, NSWEEP_W);
    rank_and_pack(a, j, b, nrmS, P0S, sig2S);

    for (int e = lane; e < 256; e += 64)
        uwd[c * 256 + e] = P0S[(e & 7) * 33 + (e >> 3)];

#pragma unroll
    for (int mm = 0; mm < 8; mm++) {
        float vq = 0.f;
#pragma unroll
        for (int i = 0; i < 16; i++) vq = fmaf(a0[i], P0S[mm * 33 + b * 16 + i], vq);
        vq += __shfl_xor(vq, 32);
        vq *= __builtin_amdgcn_rcpf(sig2S[mm]);
        if (b == 0) vwt[c * 256 + j * 8 + mm] = vq;
    }
}

// ---- Kernel 2: per (bt, c): register Jacobi SVD of x[bt][:,:,c], combine with
// w's SVD, write out[bt][h][w][c]. Block = 4 waves = 4 consecutive c of one bt.
__global__ __launch_bounds__(256, 5)
void svd_main_kernel(const float* __restrict__ x, const float* __restrict__ uwd,
                     const float* __restrict__ vwt, float* __restrict__ out) {
    __shared__ float SB[4][1056];      // stage-in [wj*33+h]; reused as outs [h*32+wj]
    __shared__ float P0S[4][8 * 33];
    __shared__ float PgS[4][256];
    __shared__ float nrmS[4][32];
    __shared__ float sig2S[4][8];

    const int t = threadIdx.x, widx = t >> 6, lane = t & 63;
    const int j = lane & 31, b = lane >> 5;
    const int bt = blockIdx.x & 1023, cg = blockIdx.x >> 10;
    const int c = cg * 4 + widx;

    // cooperative float4 load over c-minor layout; component i -> wave i's region
    const float4* x4 = (const float4*)x;
    const size_t base4 = (size_t)bt * 8192 + (size_t)cg;
#pragma unroll
    for (int k2 = 0; k2 < 4; k2++) {
        int idx = t + 256 * k2;              // idx = h*32 + wj
        float4 v = x4[base4 + (size_t)idx * 8];
        int wj = idx & 31, h = idx >> 5;
        int o = wj * 33 + h;
        SB[0][o] = v.x; SB[1][o] = v.y; SB[2][o] = v.z; SB[3][o] = v.w;
    }
    __syncthreads();

    float a[16], a0[16];
#pragma unroll
    for (int i = 0; i < 16; i++) {
        a[i] = SB[widx][j * 33 + b * 16 + i];
        a0[i] = a[i];
    }
    wavefence();

    jacobi_reg(a, j, NSWEEP_X);
    rank_and_pack(a, j, b, nrmS[widx], P0S[widx], sig2S[widx]);

    // Q[j][mm] = (A0^T a_mm / sigma^2) * vw  -> kept in registers
    const float* vw = vwt + c * 256;
    float qv[8];
#pragma unroll
    for (int mm = 0; mm < 8; mm++) {
        float vq = 0.f;
#pragma unroll
        for (int i = 0; i < 16; i++) vq = fmaf(a0[i], P0S[widx][mm * 33 + b * 16 + i], vq);
        vq += __shfl_xor(vq, 32);
        vq *= __builtin_amdgcn_rcpf(sig2S[widx][mm]);
        qv[mm] = vq * vw[j * 8 + mm];
    }

    // Pg[h][mm] = (uq*dq)[h,mm] * (uw*dw)[h,mm]
    const float* uw = uwd + c * 256;
    for (int e = lane; e < 256; e += 64)
        PgS[widx][e] = P0S[widx][(e & 7) * 33 + (e >> 3)] * uw[e];
    wavefence();

    // out[h][j] = sum_mm Pg[h][mm] * qv[mm]; lane covers h = b*16..b*16+15
#pragma unroll
    for (int i = 0; i < 16; i++) {
        int h = b * 16 + i;
        float acc = 0.f;
#pragma unroll
        for (int mm = 0; mm < 8; mm++) acc = fmaf(PgS[widx][h * 8 + mm], qv[mm], acc);
        SB[widx][h * 32 + j] = acc;
    }
    __syncthreads();

    // gather 4 c-values per (h,w) -> float4 store to out[bt][h][w][c0..c0+3]
    float4* o4 = (float4*)out;
#pragma unroll
    for (int k2 = 0; k2 < 4; k2++) {
        int idx = t + 256 * k2;
        float4 v = make_float4(SB[0][idx], SB[1][idx], SB[2][idx], SB[3][idx]);
        o4[base4 + (size_t)idx * 8] = v;
    }
}

extern "C" void kernel_launch(void* const* d_in, const int* in_sizes, int n_in,
                              void* d_out, int out_size, void* d_ws, size_t ws_size,
                              hipStream_t stream) {
    (void)in_sizes; (void)n_in; (void)out_size; (void)ws_size;
    const float* x = (const float*)d_in[0];
    const float* w = (const float*)d_in[1];
    float* out = (float*)d_out;
    float* uwd = (float*)d_ws;            // [32][32][8]
    float* vwt = uwd + 32 * 256;          // [32][32][8]

    hipLaunchKernelGGL(svd_w_kernel, dim3(32), dim3(64), 0, stream, w, uwd, vwt);
    hipLaunchKernelGGL(svd_main_kernel, dim3(8192), dim3(256), 0, stream, x, uwd, vwt, out);
}

// Round 4
// 1669.118 us; speedup vs baseline: 2.2844x; 2.2844x over previous
//
#include <hip/hip_runtime.h>
#include <hip/hip_bf16.h>

#define NSWEEP_X 8
#define NSWEEP_W 12

__device__ __forceinline__ void wavefence() {
    __builtin_amdgcn_wave_barrier();
    asm volatile("" ::: "memory");
}

// One-sided Jacobi on a 32x32 matrix held in registers across one wave.
// lane (j = lane&31, b = lane>>5) holds rows b*16..b*16+15 of column j in a[16].
// XOR ordering: masks m=1..31; pairs {j, j^m} are a perfect matching each round,
// and all 31 masks cover every column pair exactly once per sweep.
// Column norms^2 maintained incrementally (p: nn -= t*cp ; q: nn += t*cp),
// refreshed exactly once per sweep. Early exit when a full sweep does no
// rotation. After convergence column j = u_j * sigma_j (sigma cancels later).
// NOTE: keep the m-loop ROLLED (#pragma unroll 1) — full unroll spills to
// scratch (round-3 regression: WRITE_SIZE 0.37 -> 11.6 GB, VALUBusy 107 -> 38).
__device__ __forceinline__ void jacobi_reg(float a[16], int j, int nsweep) {
    for (int sw = 0; sw < nsweep; ++sw) {
        // exact norm refresh (once per sweep)
        float n0 = 0.f, n1 = 0.f, n2 = 0.f, n3 = 0.f;
#pragma unroll
        for (int i = 0; i < 16; i += 4) {
            n0 = fmaf(a[i+0], a[i+0], n0);
            n1 = fmaf(a[i+1], a[i+1], n1);
            n2 = fmaf(a[i+2], a[i+2], n2);
            n3 = fmaf(a[i+3], a[i+3], n3);
        }
        float nn = (n0 + n1) + (n2 + n3);
        nn += __shfl_xor(nn, 32);

        int did = 0;
#pragma unroll 1
        for (int m = 1; m < 32; ++m) {
            float prt[16];
#pragma unroll
            for (int i = 0; i < 16; i++) prt[i] = __shfl_xor(a[i], m);
            float c0 = 0.f, c1 = 0.f, c2 = 0.f, c3 = 0.f;
#pragma unroll
            for (int i = 0; i < 16; i += 4) {
                c0 = fmaf(a[i+0], prt[i+0], c0);
                c1 = fmaf(a[i+1], prt[i+1], c1);
                c2 = fmaf(a[i+2], prt[i+2], c2);
                c3 = fmaf(a[i+3], prt[i+3], c3);
            }
            float cp = (c0 + c1) + (c2 + c3);
            cp += __shfl_xor(cp, 32);          // full dot(own, partner)
            float on = __shfl_xor(nn, m);      // partner column norm^2
            bool isp = j < (j ^ m);
            float app = isp ? nn : on;
            float aqq = isp ? on : nn;
            if (cp * cp > 1e-12f * app * aqq) {
                float tau = (aqq - app) * __builtin_amdgcn_rcpf(2.0f * cp);
                float den = fabsf(tau) + __builtin_amdgcn_sqrtf(fmaf(tau, tau, 1.0f));
                float tt  = copysignf(__builtin_amdgcn_rcpf(den), tau);
                float cth = __builtin_amdgcn_rsqf(fmaf(tt, tt, 1.0f));
                float tsgn = isp ? -tt : tt;   // p-side: -t ; q-side: +t
                float ss   = tsgn * cth;
#pragma unroll
                for (int i = 0; i < 16; i++) a[i] = fmaf(ss, prt[i], cth * a[i]);
                nn = fmaxf(fmaf(tsgn, cp, nn), 0.0f);   // norm^2 update
                did = 1;
            }
        }
        if (!__any(did)) break;   // converged: whole sweep rotation-free
    }
}

// Rank columns by sigma^2 descending (tie-break by index). Columns with rank<8
// are packed into P0S[rk*33 + h] (h = row), their sigma^2 into sig2S[rk].
__device__ __forceinline__ void rank_and_pack(const float a[16], int j, int b,
                                              float* nrmS, float* P0S, float* sig2S) {
    float nn = 0.f;
#pragma unroll
    for (int i = 0; i < 16; i++) nn = fmaf(a[i], a[i], nn);
    nn += __shfl_xor(nn, 32);
    if (b == 0) nrmS[j] = nn;
    wavefence();
    int rk = 0;
    for (int k = 0; k < 32; k++) {
        float o = nrmS[k];
        rk += (o > nn) || (o == nn && k < j);
    }
    if (rk < 8) {
#pragma unroll
        for (int i = 0; i < 16; i++) P0S[rk * 33 + b * 16 + i] = a[i];
        if (b == 0) sig2S[rk] = nn;
    }
    wavefence();
}

// ---- Kernel 1: SVD of w[c] (32 matrices, one wave per block).
//   uwd[c][h][m] = Uw[h][m]*dw[m]   (converged column)
//   vwt[c][w][m] = Vwh[m][w]        (recovered as A0^T a_m / sigma_m^2)
__global__ __launch_bounds__(64)
void svd_w_kernel(const float* __restrict__ w, float* __restrict__ uwd,
                  float* __restrict__ vwt) {
    __shared__ float P0S[8 * 33];
    __shared__ float nrmS[32];
    __shared__ float sig2S[8];
    const int lane = threadIdx.x, j = lane & 31, b = lane >> 5;
    const int c = blockIdx.x;

    float a[16], a0[16];
#pragma unroll
    for (int i = 0; i < 16; i++) {
        a[i] = w[c * 1024 + (b * 16 + i) * 32 + j];
        a0[i] = a[i];
    }
    jacobi_reg(a, j, NSWEEP_W);
    rank_and_pack(a, j, b, nrmS, P0S, sig2S);

    for (int e = lane; e < 256; e += 64)
        uwd[c * 256 + e] = P0S[(e & 7) * 33 + (e >> 3)];

#pragma unroll
    for (int mm = 0; mm < 8; mm++) {
        float vq = 0.f;
#pragma unroll
        for (int i = 0; i < 16; i++) vq = fmaf(a0[i], P0S[mm * 33 + b * 16 + i], vq);
        vq += __shfl_xor(vq, 32);
        vq *= __builtin_amdgcn_rcpf(sig2S[mm]);
        if (b == 0) vwt[c * 256 + j * 8 + mm] = vq;
    }
}

// ---- Kernel 2: per (bt, c): register Jacobi SVD of x[bt][:,:,c], combine with
// w's SVD, write out[bt][h][w][c]. Block = 4 waves = 4 consecutive c of one bt.
__global__ __launch_bounds__(256, 5)
void svd_main_kernel(const float* __restrict__ x, const float* __restrict__ uwd,
                     const float* __restrict__ vwt, float* __restrict__ out) {
    __shared__ float SB[4][1056];      // stage-in [wj*33+h]; reused as outs [h*32+wj]
    __shared__ float P0S[4][8 * 33];
    __shared__ float PgS[4][256];
    __shared__ float nrmS[4][32];
    __shared__ float sig2S[4][8];

    const int t = threadIdx.x, widx = t >> 6, lane = t & 63;
    const int j = lane & 31, b = lane >> 5;
    const int bt = blockIdx.x & 1023, cg = blockIdx.x >> 10;
    const int c = cg * 4 + widx;

    // cooperative float4 load over c-minor layout; component i -> wave i's region
    const float4* x4 = (const float4*)x;
    const size_t base4 = (size_t)bt * 8192 + (size_t)cg;
#pragma unroll
    for (int k2 = 0; k2 < 4; k2++) {
        int idx = t + 256 * k2;              // idx = h*32 + wj
        float4 v = x4[base4 + (size_t)idx * 8];
        int wj = idx & 31, h = idx >> 5;
        int o = wj * 33 + h;
        SB[0][o] = v.x; SB[1][o] = v.y; SB[2][o] = v.z; SB[3][o] = v.w;
    }
    __syncthreads();

    float a[16], a0[16];
#pragma unroll
    for (int i = 0; i < 16; i++) {
        a[i] = SB[widx][j * 33 + b * 16 + i];
        a0[i] = a[i];
    }
    wavefence();

    jacobi_reg(a, j, NSWEEP_X);
    rank_and_pack(a, j, b, nrmS[widx], P0S[widx], sig2S[widx]);

    // Q[j][mm] = (A0^T a_mm / sigma^2) * vw  -> kept in registers
    const float* vw = vwt + c * 256;
    float qv[8];
#pragma unroll
    for (int mm = 0; mm < 8; mm++) {
        float vq = 0.f;
#pragma unroll
        for (int i = 0; i < 16; i++) vq = fmaf(a0[i], P0S[widx][mm * 33 + b * 16 + i], vq);
        vq += __shfl_xor(vq, 32);
        vq *= __builtin_amdgcn_rcpf(sig2S[widx][mm]);
        qv[mm] = vq * vw[j * 8 + mm];
    }

    // Pg[h][mm] = (uq*dq)[h,mm] * (uw*dw)[h,mm]
    const float* uw = uwd + c * 256;
    for (int e = lane; e < 256; e += 64)
        PgS[widx][e] = P0S[widx][(e & 7) * 33 + (e >> 3)] * uw[e];
    wavefence();

    // out[h][j] = sum_mm Pg[h][mm] * qv[mm]; lane covers h = b*16..b*16+15
#pragma unroll
    for (int i = 0; i < 16; i++) {
        int h = b * 16 + i;
        float acc = 0.f;
#pragma unroll
        for (int mm = 0; mm < 8; mm++) acc = fmaf(PgS[widx][h * 8 + mm], qv[mm], acc);
        SB[widx][h * 32 + j] = acc;
    }
    __syncthreads();

    // gather 4 c-values per (h,w) -> float4 store to out[bt][h][w][c0..c0+3]
    float4* o4 = (float4*)out;
#pragma unroll
    for (int k2 = 0; k2 < 4; k2++) {
        int idx = t + 256 * k2;
        float4 v = make_float4(SB[0][idx], SB[1][idx], SB[2][idx], SB[3][idx]);
        o4[base4 + (size_t)idx * 8] = v;
    }
}

extern "C" void kernel_launch(void* const* d_in, const int* in_sizes, int n_in,
                              void* d_out, int out_size, void* d_ws, size_t ws_size,
                              hipStream_t stream) {
    (void)in_sizes; (void)n_in; (void)out_size; (void)ws_size;
    const float* x = (const float*)d_in[0];
    const float* w = (const float*)d_in[1];
    float* out = (float*)d_out;
    float* uwd = (float*)d_ws;            // [32][32][8]
    float* vwt = uwd + 32 * 256;          // [32][32][8]

    hipLaunchKernelGGL(svd_w_kernel, dim3(32), dim3(64), 0, stream, w, uwd, vwt);
    hipLaunchKernelGGL(svd_main_kernel, dim3(8192), dim3(256), 0, stream, x, uwd, vwt, out);
}

// Round 5
// 1591.795 us; speedup vs baseline: 2.3954x; 1.0486x over previous
//
#include <hip/hip_runtime.h>
#include <hip/hip_bf16.h>

#define NSWEEP_X 8
#define NSWEEP_W 12

typedef float v2f __attribute__((ext_vector_type(2)));

__device__ __forceinline__ void wavefence() {
    __builtin_amdgcn_wave_barrier();
    asm volatile("" ::: "memory");
}

// Packed fp32 (VOP3P) helpers — 2 fp32 per instruction. LLVM keeps v2f as an
// adjacent VGPR pair, so these map 1:1 with no re-pairing movs.
__device__ __forceinline__ v2f pk_mul(v2f a, v2f b) {
    v2f d; asm("v_pk_mul_f32 %0, %1, %2" : "=v"(d) : "v"(a), "v"(b)); return d;
}
__device__ __forceinline__ v2f pk_fma(v2f a, v2f b, v2f c) {
    v2f d; asm("v_pk_fma_f32 %0, %1, %2, %3" : "=v"(d) : "v"(a), "v"(b), "v"(c)); return d;
}

// One-sided Jacobi on a 32x32 matrix held in registers across one wave.
// lane (j = lane&31, b = lane>>5) holds rows b*16..b*16+15 of column j as
// v2f ar[8] (row pairs). XOR ordering: masks m=1..31. Column norms^2 are
// maintained incrementally and refreshed once per sweep. Early exit when a
// full sweep does no rotation. Skip threshold 1e-10 (|cp| < 1e-5*s*s) sits
// ~3 decades above the fp32 dot's rounding noise (~3e-7*s*s), so the exit
// actually fires once truly converged (1e-12 was AT the noise floor).
// NOTE: keep the m-loop ROLLED (#pragma unroll 1) — full unroll spills
// (round-3 regression: WRITE_SIZE 0.37 -> 11.6 GB).
__device__ __forceinline__ void jacobi_reg(v2f ar[8], int j, int nsweep) {
    for (int sw = 0; sw < nsweep; ++sw) {
        // exact norm refresh (once per sweep)
        v2f nacc = {0.f, 0.f};
#pragma unroll
        for (int i = 0; i < 8; i++) nacc = pk_fma(ar[i], ar[i], nacc);
        float nn = nacc.x + nacc.y;
        nn += __shfl_xor(nn, 32);

        int did = 0;
#pragma unroll 1
        for (int m = 1; m < 32; ++m) {
            v2f prt[8];
#pragma unroll
            for (int i = 0; i < 8; i++) {
                prt[i].x = __shfl_xor(ar[i].x, m);
                prt[i].y = __shfl_xor(ar[i].y, m);
            }
            v2f cacc = {0.f, 0.f};
#pragma unroll
            for (int i = 0; i < 8; i++) cacc = pk_fma(ar[i], prt[i], cacc);
            float cp = cacc.x + cacc.y;
            cp += __shfl_xor(cp, 32);          // full dot(own, partner)
            float on = __shfl_xor(nn, m);      // partner column norm^2
            bool isp = j < (j ^ m);
            float app = isp ? nn : on;
            float aqq = isp ? on : nn;
            if (cp * cp > 1e-10f * app * aqq) {
                float tau = (aqq - app) * __builtin_amdgcn_rcpf(2.0f * cp);
                float den = fabsf(tau) + __builtin_amdgcn_sqrtf(fmaf(tau, tau, 1.0f));
                float tt  = copysignf(__builtin_amdgcn_rcpf(den), tau);
                float cth = __builtin_amdgcn_rsqf(fmaf(tt, tt, 1.0f));
                float tsgn = isp ? -tt : tt;   // p-side: -t ; q-side: +t
                float ss   = tsgn * cth;
                v2f cs2; cs2.x = cth; cs2.y = cth;
                v2f ss2; ss2.x = ss;  ss2.y = ss;
#pragma unroll
                for (int i = 0; i < 8; i++)
                    ar[i] = pk_fma(ss2, prt[i], pk_mul(cs2, ar[i]));
                nn = fmaxf(fmaf(tsgn, cp, nn), 0.0f);   // norm^2 update
                did = 1;
            }
        }
        if (!__any(did)) break;   // converged: whole sweep rotation-free
    }
}

// Rank columns by sigma^2 descending (tie-break by index). Columns with rank<8
// are packed into P0S[rk*33 + h] (h = row), their sigma^2 into sig2S[rk].
__device__ __forceinline__ void rank_and_pack(const v2f ar[8], int j, int b,
                                              float* nrmS, float* P0S, float* sig2S) {
    v2f nacc = {0.f, 0.f};
#pragma unroll
    for (int i = 0; i < 8; i++) nacc = pk_fma(ar[i], ar[i], nacc);
    float nn = nacc.x + nacc.y;
    nn += __shfl_xor(nn, 32);
    if (b == 0) nrmS[j] = nn;
    wavefence();
    int rk = 0;
    for (int k = 0; k < 32; k++) {
        float o = nrmS[k];
        rk += (o > nn) || (o == nn && k < j);
    }
    if (rk < 8) {
#pragma unroll
        for (int i = 0; i < 8; i++) {
            P0S[rk * 33 + b * 16 + 2 * i]     = ar[i].x;
            P0S[rk * 33 + b * 16 + 2 * i + 1] = ar[i].y;
        }
        if (b == 0) sig2S[rk] = nn;
    }
    wavefence();
}

// ---- Kernel 1: SVD of w[c] (32 matrices, one wave per block).
//   uwd[c][h][m] = Uw[h][m]*dw[m]   (converged column)
//   vwt[c][w][m] = Vwh[m][w]        (recovered as A0^T a_m / sigma_m^2)
__global__ __launch_bounds__(64)
void svd_w_kernel(const float* __restrict__ w, float* __restrict__ uwd,
                  float* __restrict__ vwt) {
    __shared__ float P0S[8 * 33];
    __shared__ float nrmS[32];
    __shared__ float sig2S[8];
    const int lane = threadIdx.x, j = lane & 31, b = lane >> 5;
    const int c = blockIdx.x;

    v2f ar[8], a02[8];
#pragma unroll
    for (int i = 0; i < 8; i++) {
        ar[i].x = w[c * 1024 + (b * 16 + 2 * i) * 32 + j];
        ar[i].y = w[c * 1024 + (b * 16 + 2 * i + 1) * 32 + j];
        a02[i] = ar[i];
    }
    jacobi_reg(ar, j, NSWEEP_W);
    rank_and_pack(ar, j, b, nrmS, P0S, sig2S);

    for (int e = lane; e < 256; e += 64)
        uwd[c * 256 + e] = P0S[(e & 7) * 33 + (e >> 3)];

#pragma unroll
    for (int mm = 0; mm < 8; mm++) {
        v2f acc = {0.f, 0.f};
#pragma unroll
        for (int i = 0; i < 8; i++) {
            v2f p;
            p.x = P0S[mm * 33 + b * 16 + 2 * i];
            p.y = P0S[mm * 33 + b * 16 + 2 * i + 1];
            acc = pk_fma(a02[i], p, acc);
        }
        float vq = acc.x + acc.y;
        vq += __shfl_xor(vq, 32);
        vq *= __builtin_amdgcn_rcpf(sig2S[mm]);
        if (b == 0) vwt[c * 256 + j * 8 + mm] = vq;
    }
}

// ---- Kernel 2: per (bt, c): register Jacobi SVD of x[bt][:,:,c], combine with
// w's SVD, write out[bt][h][w][c]. Block = 4 waves = 4 consecutive c of one bt.
__global__ __launch_bounds__(256, 6)
void svd_main_kernel(const float* __restrict__ x, const float* __restrict__ uwd,
                     const float* __restrict__ vwt, float* __restrict__ out) {
    __shared__ float SB[4][1056];      // stage-in [wj*33+h]; reused as outs [h*32+wj]
    __shared__ float P0S[4][8 * 33];
    __shared__ float PgS[4][256];
    __shared__ float nrmS[4][32];
    __shared__ float sig2S[4][8];

    const int t = threadIdx.x, widx = t >> 6, lane = t & 63;
    const int j = lane & 31, b = lane >> 5;
    const int bt = blockIdx.x & 1023, cg = blockIdx.x >> 10;
    const int c = cg * 4 + widx;

    // cooperative float4 load over c-minor layout; component i -> wave i's region
    const float4* x4 = (const float4*)x;
    const size_t base4 = (size_t)bt * 8192 + (size_t)cg;
#pragma unroll
    for (int k2 = 0; k2 < 4; k2++) {
        int idx = t + 256 * k2;              // idx = h*32 + wj
        float4 v = x4[base4 + (size_t)idx * 8];
        int wj = idx & 31, h = idx >> 5;
        int o = wj * 33 + h;
        SB[0][o] = v.x; SB[1][o] = v.y; SB[2][o] = v.z; SB[3][o] = v.w;
    }
    __syncthreads();

    // load own column into registers (SB stays intact: a0 re-read after Jacobi)
    v2f ar[8];
#pragma unroll
    for (int i = 0; i < 8; i++) {
        ar[i].x = SB[widx][j * 33 + b * 16 + 2 * i];
        ar[i].y = SB[widx][j * 33 + b * 16 + 2 * i + 1];
    }
    wavefence();

    jacobi_reg(ar, j, NSWEEP_X);
    rank_and_pack(ar, j, b, nrmS[widx], P0S[widx], sig2S[widx]);

    // Q[j][mm] = (A0^T a_mm / sigma^2) * vw  -> kept in registers.
    // a0 re-loaded from SB (kept out of registers during Jacobi).
    v2f a02[8];
#pragma unroll
    for (int i = 0; i < 8; i++) {
        a02[i].x = SB[widx][j * 33 + b * 16 + 2 * i];
        a02[i].y = SB[widx][j * 33 + b * 16 + 2 * i + 1];
    }
    const float* vw = vwt + c * 256;
    float qv[8];
#pragma unroll
    for (int mm = 0; mm < 8; mm++) {
        v2f acc = {0.f, 0.f};
#pragma unroll
        for (int i = 0; i < 8; i++) {
            v2f p;
            p.x = P0S[widx][mm * 33 + b * 16 + 2 * i];
            p.y = P0S[widx][mm * 33 + b * 16 + 2 * i + 1];
            acc = pk_fma(a02[i], p, acc);
        }
        float vq = acc.x + acc.y;
        vq += __shfl_xor(vq, 32);
        vq *= __builtin_amdgcn_rcpf(sig2S[widx][mm]);
        qv[mm] = vq * vw[j * 8 + mm];
    }

    // Pg[h][mm] = (uq*dq)[h,mm] * (uw*dw)[h,mm]
    const float* uw = uwd + c * 256;
    for (int e = lane; e < 256; e += 64)
        PgS[widx][e] = P0S[widx][(e & 7) * 33 + (e >> 3)] * uw[e];
    wavefence();

    // out[h][j] = sum_mm Pg[h][mm] * qv[mm]; lane covers h = b*16..b*16+15
#pragma unroll
    for (int i = 0; i < 16; i++) {
        int h = b * 16 + i;
        float acc = 0.f;
#pragma unroll
        for (int mm = 0; mm < 8; mm++) acc = fmaf(PgS[widx][h * 8 + mm], qv[mm], acc);
        SB[widx][h * 32 + j] = acc;
    }
    __syncthreads();

    // gather 4 c-values per (h,w) -> float4 store to out[bt][h][w][c0..c0+3]
    float4* o4 = (float4*)out;
#pragma unroll
    for (int k2 = 0; k2 < 4; k2++) {
        int idx = t + 256 * k2;
        float4 v = make_float4(SB[0][idx], SB[1][idx], SB[2][idx], SB[3][idx]);
        o4[base4 + (size_t)idx * 8] = v;
    }
}

extern "C" void kernel_launch(void* const* d_in, const int* in_sizes, int n_in,
                              void* d_out, int out_size, void* d_ws, size_t ws_size,
                              hipStream_t stream) {
    (void)in_sizes; (void)n_in; (void)out_size; (void)ws_size;
    const float* x = (const float*)d_in[0];
    const float* w = (const float*)d_in[1];
    float* out = (float*)d_out;
    float* uwd = (float*)d_ws;            // [32][32][8]
    float* vwt = uwd + 32 * 256;          // [32][32][8]

    hipLaunchKernelGGL(svd_w_kernel, dim3(32), dim3(64), 0, stream, w, uwd, vwt);
    hipLaunchKernelGGL(svd_main_kernel, dim3(8192), dim3(256), 0, stream, x, uwd, vwt, out);
}

// Round 6
// 1507.863 us; speedup vs baseline: 2.5287x; 1.0557x over previous
//
#include <hip/hip_runtime.h>
#include <hip/hip_bf16.h>

#define NSWEEP_X 8
#define NSWEEP_W 12

// LDS aliasing layout inside SBig[widx][1056] (floats), post-staging:
#define OFF_PG   0     // 256: Pg[h][m]
#define OFF_NRM  256   // 32
#define OFF_SIG  288   // 8
#define OFF_P0   296   // 264: packed top-8 columns (dead before OUT)
#define OFF_OUT  296   // 512: half-pass output transpose (aliases P0)

typedef float v2f __attribute__((ext_vector_type(2)));

__device__ __forceinline__ void wavefence() {
    __builtin_amdgcn_wave_barrier();
    asm volatile("" ::: "memory");
}

// Packed fp32 (VOP3P) helpers — 2 fp32 per instruction.
__device__ __forceinline__ v2f pk_mul(v2f a, v2f b) {
    v2f d; asm("v_pk_mul_f32 %0, %1, %2" : "=v"(d) : "v"(a), "v"(b)); return d;
}
__device__ __forceinline__ v2f pk_fma(v2f a, v2f b, v2f c) {
    v2f d; asm("v_pk_fma_f32 %0, %1, %2, %3" : "=v"(d) : "v"(a), "v"(b), "v"(c)); return d;
}

// One-sided Jacobi on a 32x32 matrix in registers across one wave.
// lane (j = lane&31, b = lane>>5) holds rows b*16..b*16+15 of column j as
// v2f ar[8]. XOR ordering (masks 1..31). Norms^2 maintained incrementally,
// refreshed once per sweep. Skip threshold is ABSOLUTE: cp^2 > (4e-6*nmax)^2,
// where nmax = max column norm^2 — the fp32 dot noise is ~2e-6*nmax, so a
// relative (app*aqq) threshold never lets small-sigma pairs stop rotating
// on noise, and the all-skip early exit below would never fire (round-5 bug).
// NOTE: keep the m-loop ROLLED — full unroll spills (round-3 regression).
__device__ __forceinline__ void jacobi_reg(v2f ar[8], int j, int nsweep) {
    for (int sw = 0; sw < nsweep; ++sw) {
        // exact norm refresh + nmax (once per sweep)
        v2f nacc = {0.f, 0.f};
#pragma unroll
        for (int i = 0; i < 8; i++) nacc = pk_fma(ar[i], ar[i], nacc);
        float nn = nacc.x + nacc.y;
        nn += __shfl_xor(nn, 32);
        float nmax = nn;
#pragma unroll
        for (int mk = 16; mk >= 1; mk >>= 1) nmax = fmaxf(nmax, __shfl_xor(nmax, mk));
        const float thr = 1.6e-11f * nmax * nmax;   // (4e-6 * nmax)^2

        int did = 0;
#pragma unroll 1
        for (int m = 1; m < 32; ++m) {
            v2f prt[8];
#pragma unroll
            for (int i = 0; i < 8; i++) {
                prt[i].x = __shfl_xor(ar[i].x, m);
                prt[i].y = __shfl_xor(ar[i].y, m);
            }
            v2f cacc = {0.f, 0.f};
#pragma unroll
            for (int i = 0; i < 8; i++) cacc = pk_fma(ar[i], prt[i], cacc);
            float cp = cacc.x + cacc.y;
            cp += __shfl_xor(cp, 32);          // full dot(own, partner)
            if (cp * cp > thr) {
                float on = __shfl_xor(nn, m);  // partner column norm^2
                bool isp = j < (j ^ m);
                float app = isp ? nn : on;
                float aqq = isp ? on : nn;
                float tau = (aqq - app) * __builtin_amdgcn_rcpf(2.0f * cp);
                float den = fabsf(tau) + __builtin_amdgcn_sqrtf(fmaf(tau, tau, 1.0f));
                float tt  = copysignf(__builtin_amdgcn_rcpf(den), tau);
                float cth = __builtin_amdgcn_rsqf(fmaf(tt, tt, 1.0f));
                float tsgn = isp ? -tt : tt;   // p-side: -t ; q-side: +t
                float ss   = tsgn * cth;
                v2f cs2; cs2.x = cth; cs2.y = cth;
                v2f ss2; ss2.x = ss;  ss2.y = ss;
#pragma unroll
                for (int i = 0; i < 8; i++)
                    ar[i] = pk_fma(ss2, prt[i], pk_mul(cs2, ar[i]));
                nn = fmaxf(fmaf(tsgn, cp, nn), 0.0f);   // norm^2 update
                did = 1;
            }
        }
        if (!__any(did)) break;   // converged: whole sweep rotation-free
    }
}

// Rank columns by sigma^2 descending (tie-break by index). Columns with rank<8
// are packed into P0S[rk*33 + h], their sigma^2 into sig2S[rk].
__device__ __forceinline__ void rank_and_pack(const v2f ar[8], int j, int b,
                                              float* nrmS, float* P0S, float* sig2S) {
    v2f nacc = {0.f, 0.f};
#pragma unroll
    for (int i = 0; i < 8; i++) nacc = pk_fma(ar[i], ar[i], nacc);
    float nn = nacc.x + nacc.y;
    nn += __shfl_xor(nn, 32);
    if (b == 0) nrmS[j] = nn;
    wavefence();
    int rk = 0;
    for (int k = 0; k < 32; k++) {
        float o = nrmS[k];
        rk += (o > nn) || (o == nn && k < j);
    }
    if (rk < 8) {
#pragma unroll
        for (int i = 0; i < 8; i++) {
            P0S[rk * 33 + b * 16 + 2 * i]     = ar[i].x;
            P0S[rk * 33 + b * 16 + 2 * i + 1] = ar[i].y;
        }
        if (b == 0) sig2S[rk] = nn;
    }
    wavefence();
}

// ---- Kernel 1: SVD of w[c] (32 matrices, one wave per block).
__global__ __launch_bounds__(64)
void svd_w_kernel(const float* __restrict__ w, float* __restrict__ uwd,
                  float* __restrict__ vwt) {
    __shared__ float P0S[8 * 33];
    __shared__ float nrmS[32];
    __shared__ float sig2S[8];
    const int lane = threadIdx.x, j = lane & 31, b = lane >> 5;
    const int c = blockIdx.x;

    v2f ar[8], a02[8];
#pragma unroll
    for (int i = 0; i < 8; i++) {
        ar[i].x = w[c * 1024 + (b * 16 + 2 * i) * 32 + j];
        ar[i].y = w[c * 1024 + (b * 16 + 2 * i + 1) * 32 + j];
        a02[i] = ar[i];
    }
    jacobi_reg(ar, j, NSWEEP_W);
    rank_and_pack(ar, j, b, nrmS, P0S, sig2S);

    for (int e = lane; e < 256; e += 64)
        uwd[c * 256 + e] = P0S[(e & 7) * 33 + (e >> 3)];

#pragma unroll
    for (int mm = 0; mm < 8; mm++) {
        v2f acc = {0.f, 0.f};
#pragma unroll
        for (int i = 0; i < 8; i++) {
            v2f p;
            p.x = P0S[mm * 33 + b * 16 + 2 * i];
            p.y = P0S[mm * 33 + b * 16 + 2 * i + 1];
            acc = pk_fma(a02[i], p, acc);
        }
        float vq = acc.x + acc.y;
        vq += __shfl_xor(vq, 32);
        vq *= __builtin_amdgcn_rcpf(sig2S[mm]);
        if (b == 0) vwt[c * 256 + j * 8 + mm] = vq;
    }
}

// ---- Kernel 2: per (bt, c): register Jacobi SVD of x[bt][:,:,c], combine with
// w's SVD, write out[bt][h][w][c]. Block = 4 waves = 4 consecutive c of one bt.
// LDS: single 16.9KB buffer, aliased across phases -> 8 blocks/CU (100% occ).
__global__ __launch_bounds__(256, 8)
void svd_main_kernel(const float* __restrict__ x, const float* __restrict__ uwd,
                     const float* __restrict__ vwt, float* __restrict__ out) {
    __shared__ float SBig[4][1056];

    const int t = threadIdx.x, widx = t >> 6, lane = t & 63;
    const int j = lane & 31, b = lane >> 5;
    const int bt = blockIdx.x & 1023, cg = blockIdx.x >> 10;
    const int c = cg * 4 + widx;

    // cooperative float4 load over c-minor layout; component i -> wave i region
    const float4* x4 = (const float4*)x;
    const size_t base4 = (size_t)bt * 8192 + (size_t)cg;
#pragma unroll
    for (int k2 = 0; k2 < 4; k2++) {
        int idx = t + 256 * k2;              // idx = h*32 + wj
        float4 v = x4[base4 + (size_t)idx * 8];
        int wj = idx & 31, h = idx >> 5;
        int o = wj * 33 + h;
        SBig[0][o] = v.x; SBig[1][o] = v.y; SBig[2][o] = v.z; SBig[3][o] = v.w;
    }
    __syncthreads();

    // own column into registers; a0 KEPT in regs (frees staging LDS for alias)
    v2f ar[8], a02[8];
#pragma unroll
    for (int i = 0; i < 8; i++) {
        ar[i].x = SBig[widx][j * 33 + b * 16 + 2 * i];
        ar[i].y = SBig[widx][j * 33 + b * 16 + 2 * i + 1];
        a02[i] = ar[i];
    }
    wavefence();
    // staging data now dead; from here each wave touches only SBig[widx]
    float* PgS  = SBig[widx] + OFF_PG;
    float* nrmS = SBig[widx] + OFF_NRM;
    float* sigS = SBig[widx] + OFF_SIG;
    float* P0S  = SBig[widx] + OFF_P0;

    jacobi_reg(ar, j, NSWEEP_X);
    rank_and_pack(ar, j, b, nrmS, P0S, sigS);

    // Q[j][mm] = (A0^T a_mm / sigma^2) * vw  -> registers
    const float* vw = vwt + c * 256;
    float qv[8];
#pragma unroll
    for (int mm = 0; mm < 8; mm++) {
        v2f acc = {0.f, 0.f};
#pragma unroll
        for (int i = 0; i < 8; i++) {
            v2f p;
            p.x = P0S[mm * 33 + b * 16 + 2 * i];
            p.y = P0S[mm * 33 + b * 16 + 2 * i + 1];
            acc = pk_fma(a02[i], p, acc);
        }
        float vq = acc.x + acc.y;
        vq += __shfl_xor(vq, 32);
        vq *= __builtin_amdgcn_rcpf(sigS[mm]);
        qv[mm] = vq * vw[j * 8 + mm];
    }

    // Pg[h][mm] = (uq*dq)[h,mm] * (uw*dw)[h,mm]
    const float* uw = uwd + c * 256;
    for (int e = lane; e < 256; e += 64)
        PgS[e] = P0S[(e & 7) * 33 + (e >> 3)] * uw[e];
    wavefence();

    // out in two half-passes (h covers {p*8..p*8+7} U {16+p*8..16+p*8+7});
    // outs region aliases P0S (dead after PgS/qv above).
    float4* o4 = (float4*)out;
    for (int p = 0; p < 2; ++p) {
#pragma unroll
        for (int i = 0; i < 8; i++) {
            int h = b * 16 + p * 8 + i;
            float acc = 0.f;
#pragma unroll
            for (int mm = 0; mm < 8; mm++) acc = fmaf(PgS[h * 8 + mm], qv[mm], acc);
            SBig[widx][OFF_OUT + (b * 8 + i) * 32 + j] = acc;
        }
        __syncthreads();
#pragma unroll
        for (int k2 = 0; k2 < 2; k2++) {
            int l = t + 256 * k2;
            int lh = l >> 5, wj = l & 31;
            int gh = (lh < 8) ? (p * 8 + lh) : (8 + p * 8 + lh);  // lh>=8 -> 16+p*8+(lh-8)
            float4 v = make_float4(SBig[0][OFF_OUT + l], SBig[1][OFF_OUT + l],
                                   SBig[2][OFF_OUT + l], SBig[3][OFF_OUT + l]);
            o4[base4 + (size_t)(gh * 32 + wj) * 8] = v;
        }
        if (p == 0) __syncthreads();   // gather-read done before pass-2 rewrite
    }
}

extern "C" void kernel_launch(void* const* d_in, const int* in_sizes, int n_in,
                              void* d_out, int out_size, void* d_ws, size_t ws_size,
                              hipStream_t stream) {
    (void)in_sizes; (void)n_in; (void)out_size; (void)ws_size;
    const float* x = (const float*)d_in[0];
    const float* w = (const float*)d_in[1];
    float* out = (float*)d_out;
    float* uwd = (float*)d_ws;            // [32][32][8]
    float* vwt = uwd + 32 * 256;          // [32][32][8]

    hipLaunchKernelGGL(svd_w_kernel, dim3(32), dim3(64), 0, stream, w, uwd, vwt);
    hipLaunchKernelGGL(svd_main_kernel, dim3(8192), dim3(256), 0, stream, x, uwd, vwt, out);
}

// Round 8
// 1507.059 us; speedup vs baseline: 2.5300x; 1.0005x over previous
//
#include <hip/hip_runtime.h>
#include <hip/hip_bf16.h>

#define NSWEEP_X 8
#define NSWEEP_W 12

// LDS aliasing layout inside SBig[widx][1056] (floats), post-staging:
#define OFF_PG   0     // 256: Pg[h][m]
#define OFF_NRM  256   // 32
#define OFF_SIG  288   // 8
#define OFF_P0   296   // 264: packed top-8 columns (dead before OUT)
#define OFF_OUT  296   // 512: half-pass output transpose (aliases P0)

typedef float v2f __attribute__((ext_vector_type(2)));

__device__ __forceinline__ void wavefence() {
    __builtin_amdgcn_wave_barrier();
    asm volatile("" ::: "memory");
}

// Packed fp32 (VOP3P) helpers — 2 fp32 per instruction.
__device__ __forceinline__ v2f pk_mul(v2f a, v2f b) {
    v2f d; asm("v_pk_mul_f32 %0, %1, %2" : "=v"(d) : "v"(a), "v"(b)); return d;
}
__device__ __forceinline__ v2f pk_fma(v2f a, v2f b, v2f c) {
    v2f d; asm("v_pk_fma_f32 %0, %1, %2, %3" : "=v"(d) : "v"(a), "v"(b), "v"(c)); return d;
}

// Cross-half (lane ^ 32) sum. NOTE: round-7 NaN post-mortem — the
// v_permlane32_swap_b32 inline-asm version had both "+v" operands fed the
// same SSA value; regalloc coalesced them into ONE register (self-swap =
// garbage). Keep the proven shfl form; both halves add in the same order
// (own partial first), so the result is bitwise-identical across the pair.
__device__ __forceinline__ float xhalf_sum(float v) {
    return v + __shfl_xor(v, 32);
}

__device__ __forceinline__ float bperm(int addr, float v) {
    return __int_as_float(__builtin_amdgcn_ds_bpermute(addr, __float_as_int(v)));
}

// One-sided Jacobi on a 32x32 matrix in registers across one wave.
// lane (j = lane&31, b = lane>>5) holds rows b*16..b*16+15 of column j as
// v2f ar[8]. XOR ordering (masks 1..31). Norms^2 maintained incrementally,
// refreshed once per sweep. Absolute skip threshold (4e-6*nmax)^2 sits above
// the fp32 dot noise floor, so the all-skip early exit fires when converged.
// LOCAL-TAU: tau computed from (on - nn) on EACH side; t is odd in tau, so
// the update a' = c*a - s*prt and nn' = nn - t*cp is side-uniform (no
// p/q-side selects; p-side gives c*p - s*q, q-side s*p + c*q). Both lanes
// of a pair compute bitwise-equal cp (same products, same add order), so
// skip decisions stay pair-symmetric.
// NOTE: keep the m-loop ROLLED — full unroll spills (round-3 regression).
__device__ __forceinline__ void jacobi_reg(v2f ar[8], int lane, int nsweep) {
    for (int sw = 0; sw < nsweep; ++sw) {
        // exact norm refresh + nmax (once per sweep)
        v2f nacc = {0.f, 0.f};
#pragma unroll
        for (int i = 0; i < 8; i++) nacc = pk_fma(ar[i], ar[i], nacc);
        float nn = xhalf_sum(nacc.x + nacc.y);
        float nmax = nn;
#pragma unroll
        for (int mk = 16; mk >= 1; mk >>= 1) nmax = fmaxf(nmax, __shfl_xor(nmax, mk));
        const float thr = 1.6e-11f * nmax * nmax;   // (4e-6 * nmax)^2

        int did = 0;
#pragma unroll 1
        for (int m = 1; m < 32; ++m) {
            const int addr = (lane ^ m) << 2;   // one shared bpermute address
            v2f prt[8];
#pragma unroll
            for (int i = 0; i < 8; i++) {
                prt[i].x = bperm(addr, ar[i].x);
                prt[i].y = bperm(addr, ar[i].y);
            }
            float on = bperm(addr, nn);         // partner column norm^2
            v2f cacc = {0.f, 0.f};
#pragma unroll
            for (int i = 0; i < 8; i++) cacc = pk_fma(ar[i], prt[i], cacc);
            float cp = xhalf_sum(cacc.x + cacc.y);   // full dot(own, partner)
            if (cp * cp > thr) {
                float tau = (on - nn) * __builtin_amdgcn_rcpf(2.0f * cp);
                float den = fabsf(tau) + __builtin_amdgcn_sqrtf(fmaf(tau, tau, 1.0f));
                float tt  = copysignf(__builtin_amdgcn_rcpf(den), tau);
                float cth = __builtin_amdgcn_rsqf(fmaf(tt, tt, 1.0f));
                float msn = tt * (-cth);        // -(s)
                v2f cs2; cs2.x = cth; cs2.y = cth;
                v2f ms2; ms2.x = msn; ms2.y = msn;
#pragma unroll
                for (int i = 0; i < 8; i++)
                    ar[i] = pk_fma(ms2, prt[i], pk_mul(cs2, ar[i]));
                nn = fmaxf(fmaf(-tt, cp, nn), 0.0f);   // nn' = nn - t*cp
                did = 1;
            }
        }
        if (!__any(did)) break;   // converged: whole sweep rotation-free
    }
}

// Rank columns by sigma^2 descending (tie-break by index). Columns with rank<8
// are packed into P0S[rk*33 + h], their sigma^2 into sig2S[rk].
__device__ __forceinline__ void rank_and_pack(const v2f ar[8], int j, int b,
                                              float* nrmS, float* P0S, float* sig2S) {
    v2f nacc = {0.f, 0.f};
#pragma unroll
    for (int i = 0; i < 8; i++) nacc = pk_fma(ar[i], ar[i], nacc);
    float nn = xhalf_sum(nacc.x + nacc.y);
    if (b == 0) nrmS[j] = nn;
    wavefence();
    int rk = 0;
    for (int k = 0; k < 32; k++) {
        float o = nrmS[k];
        rk += (o > nn) || (o == nn && k < j);
    }
    if (rk < 8) {
#pragma unroll
        for (int i = 0; i < 8; i++) {
            P0S[rk * 33 + b * 16 + 2 * i]     = ar[i].x;
            P0S[rk * 33 + b * 16 + 2 * i + 1] = ar[i].y;
        }
        if (b == 0) sig2S[rk] = nn;
    }
    wavefence();
}

// ---- Kernel 1: SVD of w[c] (32 matrices, one wave per block).
__global__ __launch_bounds__(64)
void svd_w_kernel(const float* __restrict__ w, float* __restrict__ uwd,
                  float* __restrict__ vwt) {
    __shared__ float P0S[8 * 33];
    __shared__ float nrmS[32];
    __shared__ float sig2S[8];
    const int lane = threadIdx.x, j = lane & 31, b = lane >> 5;
    const int c = blockIdx.x;

    v2f ar[8], a02[8];
#pragma unroll
    for (int i = 0; i < 8; i++) {
        ar[i].x = w[c * 1024 + (b * 16 + 2 * i) * 32 + j];
        ar[i].y = w[c * 1024 + (b * 16 + 2 * i + 1) * 32 + j];
        a02[i] = ar[i];
    }
    jacobi_reg(ar, lane, NSWEEP_W);
    rank_and_pack(ar, j, b, nrmS, P0S, sig2S);

    for (int e = lane; e < 256; e += 64)
        uwd[c * 256 + e] = P0S[(e & 7) * 33 + (e >> 3)];

#pragma unroll
    for (int mm = 0; mm < 8; mm++) {
        v2f acc = {0.f, 0.f};
#pragma unroll
        for (int i = 0; i < 8; i++) {
            v2f p;
            p.x = P0S[mm * 33 + b * 16 + 2 * i];
            p.y = P0S[mm * 33 + b * 16 + 2 * i + 1];
            acc = pk_fma(a02[i], p, acc);
        }
        float vq = xhalf_sum(acc.x + acc.y);
        vq *= __builtin_amdgcn_rcpf(sig2S[mm]);
        if (b == 0) vwt[c * 256 + j * 8 + mm] = vq;
    }
}

// ---- Kernel 2: per (bt, c): register Jacobi SVD of x[bt][:,:,c], combine with
// w's SVD, write out[bt][h][w][c]. Block = 4 waves = 4 consecutive c of one bt.
// LDS: single 16.9KB buffer, aliased across phases -> 8 blocks/CU.
__global__ __launch_bounds__(256, 8)
void svd_main_kernel(const float* __restrict__ x, const float* __restrict__ uwd,
                     const float* __restrict__ vwt, float* __restrict__ out) {
    __shared__ float SBig[4][1056];

    const int t = threadIdx.x, widx = t >> 6, lane = t & 63;
    const int j = lane & 31, b = lane >> 5;
    const int bt = blockIdx.x & 1023, cg = blockIdx.x >> 10;
    const int c = cg * 4 + widx;

    // cooperative float4 load over c-minor layout; component i -> wave i region
    const float4* x4 = (const float4*)x;
    const size_t base4 = (size_t)bt * 8192 + (size_t)cg;
#pragma unroll
    for (int k2 = 0; k2 < 4; k2++) {
        int idx = t + 256 * k2;              // idx = h*32 + wj
        float4 v = x4[base4 + (size_t)idx * 8];
        int wj = idx & 31, h = idx >> 5;
        int o = wj * 33 + h;
        SBig[0][o] = v.x; SBig[1][o] = v.y; SBig[2][o] = v.z; SBig[3][o] = v.w;
    }
    __syncthreads();

    // own column into registers; a0 KEPT in regs (frees staging LDS for alias)
    v2f ar[8], a02[8];
#pragma unroll
    for (int i = 0; i < 8; i++) {
        ar[i].x = SBig[widx][j * 33 + b * 16 + 2 * i];
        ar[i].y = SBig[widx][j * 33 + b * 16 + 2 * i + 1];
        a02[i] = ar[i];
    }
    wavefence();
    // staging data now dead; from here each wave touches only SBig[widx]
    float* PgS  = SBig[widx] + OFF_PG;
    float* nrmS = SBig[widx] + OFF_NRM;
    float* sigS = SBig[widx] + OFF_SIG;
    float* P0S  = SBig[widx] + OFF_P0;

    jacobi_reg(ar, lane, NSWEEP_X);
    rank_and_pack(ar, j, b, nrmS, P0S, sigS);

    // Q[j][mm] = (A0^T a_mm / sigma^2) * vw  -> registers
    const float* vw = vwt + c * 256;
    float qv[8];
#pragma unroll
    for (int mm = 0; mm < 8; mm++) {
        v2f acc = {0.f, 0.f};
#pragma unroll
        for (int i = 0; i < 8; i++) {
            v2f p;
            p.x = P0S[mm * 33 + b * 16 + 2 * i];
            p.y = P0S[mm * 33 + b * 16 + 2 * i + 1];
            acc = pk_fma(a02[i], p, acc);
        }
        float vq = xhalf_sum(acc.x + acc.y);
        vq *= __builtin_amdgcn_rcpf(sigS[mm]);
        qv[mm] = vq * vw[j * 8 + mm];
    }

    // Pg[h][mm] = (uq*dq)[h,mm] * (uw*dw)[h,mm]
    const float* uw = uwd + c * 256;
    for (int e = lane; e < 256; e += 64)
        PgS[e] = P0S[(e & 7) * 33 + (e >> 3)] * uw[e];
    wavefence();

    // out in two half-passes; outs region aliases P0S (dead after PgS/qv).
    float4* o4 = (float4*)out;
    for (int p = 0; p < 2; ++p) {
#pragma unroll
        for (int i = 0; i < 8; i++) {
            int h = b * 16 + p * 8 + i;
            float acc = 0.f;
#pragma unroll
            for (int mm = 0; mm < 8; mm++) acc = fmaf(PgS[h * 8 + mm], qv[mm], acc);
            SBig[widx][OFF_OUT + (b * 8 + i) * 32 + j] = acc;
        }
        __syncthreads();
#pragma unroll
        for (int k2 = 0; k2 < 2; k2++) {
            int l = t + 256 * k2;
            int lh = l >> 5, wj = l & 31;
            int gh = (lh < 8) ? (p * 8 + lh) : (8 + p * 8 + lh);
            float4 v = make_float4(SBig[0][OFF_OUT + l], SBig[1][OFF_OUT + l],
                                   SBig[2][OFF_OUT + l], SBig[3][OFF_OUT + l]);
            o4[base4 + (size_t)(gh * 32 + wj) * 8] = v;
        }
        if (p == 0) __syncthreads();   // gather-read done before pass-2 rewrite
    }
}

extern "C" void kernel_launch(void* const* d_in, const int* in_sizes, int n_in,
                              void* d_out, int out_size, void* d_ws, size_t ws_size,
                              hipStream_t stream) {
    (void)in_sizes; (void)n_in; (void)out_size; (void)ws_size;
    const float* x = (const float*)d_in[0];
    const float* w = (const float*)d_in[1];
    float* out = (float*)d_out;
    float* uwd = (float*)d_ws;            // [32][32][8]
    float* vwt = uwd + 32 * 256;          // [32][32][8]

    hipLaunchKernelGGL(svd_w_kernel, dim3(32), dim3(64), 0, stream, w, uwd, vwt);
    hipLaunchKernelGGL(svd_main_kernel, dim3(8192), dim3(256), 0, stream, x, uwd, vwt, out);
}

// Round 9
// 1356.469 us; speedup vs baseline: 2.8109x; 1.1110x over previous
//
#include <hip/hip_runtime.h>
#include <hip/hip_bf16.h>

#define NSWEEP_X 8
#define NSWEEP_W 12

typedef float v2f __attribute__((ext_vector_type(2)));

__device__ __forceinline__ void wavefence() {
    __builtin_amdgcn_wave_barrier();
    asm volatile("" ::: "memory");
}

// Packed fp32 (VOP3P) helpers — 2 fp32 per instruction.
__device__ __forceinline__ v2f pk_mul(v2f a, v2f b) {
    v2f d; asm("v_pk_mul_f32 %0, %1, %2" : "=v"(d) : "v"(a), "v"(b)); return d;
}
__device__ __forceinline__ v2f pk_fma(v2f a, v2f b, v2f c) {
    v2f d; asm("v_pk_fma_f32 %0, %1, %2, %3" : "=v"(d) : "v"(a), "v"(b), "v"(c)); return d;
}

__device__ __forceinline__ float bperm(int addr, float v) {
    return __int_as_float(__builtin_amdgcn_ds_bpermute(addr, __float_as_int(v)));
}

// One-sided Jacobi, FULL column per lane, TWO matrices per wave:
// lanes 0-31 = matrix A columns, lanes 32-63 = matrix B columns (independent).
// Each lane holds its 32-row column as v2f col[16]. XOR ordering (m=1..31)
// stays within each 32-lane half (bperm addr preserves bit5). The pair dot
// cp is LANE-LOCAL (16 pk_fma + 1 add) — no cross-half reduce on the chain.
// Local-tau update (r7/r8-proven): tau from (on-nn) per side; col' =
// c*col - s*prt, nn' = nn - t*cp is side-uniform; both lanes of a pair get
// bitwise-equal cp (commutative products, same order) -> symmetric skips.
// Absolute skip threshold (4e-6*nmax)^2 sits above fp32 dot noise -> the
// all-sweep-skip early exit fires once converged.
// NOTE: keep the m-loop ROLLED — full unroll spills (round-3 regression).
__device__ __forceinline__ void jacobi2(v2f col[16], int lane, int nsweep) {
    const int lb = lane << 2;
    for (int sw = 0; sw < nsweep; ++sw) {
        v2f nacc = {0.f, 0.f};
#pragma unroll
        for (int i = 0; i < 16; i++) nacc = pk_fma(col[i], col[i], nacc);
        float nn = nacc.x + nacc.y;          // full own-column norm^2 (local!)
        float nmax = nn;                     // per-matrix max via 32-group butterfly
#pragma unroll
        for (int mk = 16; mk >= 1; mk >>= 1) nmax = fmaxf(nmax, __shfl_xor(nmax, mk));
        const float thr = 1.6e-11f * nmax * nmax;   // (4e-6 * nmax)^2

        int did = 0;
#pragma unroll 1
        for (int m = 1; m < 32; ++m) {
            const int addr = lb ^ (m << 2);  // stays within own 32-lane half
            v2f prt[16];
#pragma unroll
            for (int i = 0; i < 16; i++) {
                prt[i].x = bperm(addr, col[i].x);
                prt[i].y = bperm(addr, col[i].y);
            }
            float on = bperm(addr, nn);      // partner norm^2
            v2f cacc = {0.f, 0.f};
#pragma unroll
            for (int i = 0; i < 16; i++) cacc = pk_fma(col[i], prt[i], cacc);
            float cp = cacc.x + cacc.y;      // FULL dot, lane-local
            if (cp * cp > thr) {
                float tau = (on - nn) * __builtin_amdgcn_rcpf(2.0f * cp);
                float den = fabsf(tau) + __builtin_amdgcn_sqrtf(fmaf(tau, tau, 1.0f));
                float tt  = copysignf(__builtin_amdgcn_rcpf(den), tau);
                float cth = __builtin_amdgcn_rsqf(fmaf(tt, tt, 1.0f));
                float msn = tt * (-cth);
                v2f cs2; cs2.x = cth; cs2.y = cth;
                v2f ms2; ms2.x = msn; ms2.y = msn;
#pragma unroll
                for (int i = 0; i < 16; i++)
                    col[i] = pk_fma(ms2, prt[i], pk_mul(cs2, col[i]));
                nn = fmaxf(fmaf(-tt, cp, nn), 0.0f);
                did = 1;
            }
        }
        if (!__any(did)) break;   // both matrices converged
    }
}

// Rank own column by sigma^2 (descending, tie-break index) within the 32-lane
// group; rk<8 lanes pack their column into P0m[rk*32 + h], sigma^2 into sigm.
__device__ __forceinline__ void rank_pack2(const v2f col[16], int jl,
                                           float* P0m, float* nrmm, float* sigm) {
    v2f nacc = {0.f, 0.f};
#pragma unroll
    for (int i = 0; i < 16; i++) nacc = pk_fma(col[i], col[i], nacc);
    float nn = nacc.x + nacc.y;
    nrmm[jl] = nn;
    wavefence();
    int rk = 0;
    for (int k = 0; k < 32; k++) {
        float o = nrmm[k];
        rk += (o > nn) || (o == nn && k < jl);
    }
    if (rk < 8) {
#pragma unroll
        for (int i = 0; i < 16; i++)
            *(v2f*)&P0m[rk * 32 + 2 * i] = col[i];
        sigm[rk] = nn;
    }
    wavefence();
}

// ---- Kernel 1: SVD of w[c]; one wave per block handles TWO c channels.
//   uwd[c][h][m] = Uw[h][m]*dw[m]   (converged column)
//   vwt[c][w][m] = Vwh[m][w]        (A0^T a_m / sigma_m^2)
__global__ __launch_bounds__(64)
void svd_w_kernel(const float* __restrict__ w, float* __restrict__ uwd,
                  float* __restrict__ vwt) {
    __shared__ float P0w[512];   // [hb*256 + mm*32 + h]
    __shared__ float nrmw[64];
    __shared__ float sigw[16];
    const int lane = threadIdx.x, jl = lane & 31, hb = lane >> 5;
    const int c = blockIdx.x * 2 + hb;

    v2f col[16], a0[16];
#pragma unroll
    for (int i = 0; i < 16; i++) {
        col[i].x = w[c * 1024 + (2 * i) * 32 + jl];
        col[i].y = w[c * 1024 + (2 * i + 1) * 32 + jl];
        a0[i] = col[i];
    }
    jacobi2(col, lane, NSWEEP_W);
    rank_pack2(col, jl, P0w + hb * 256, nrmw + hb * 32, sigw + hb * 8);

    for (int e = jl; e < 256; e += 32)
        uwd[c * 256 + e] = P0w[hb * 256 + (e & 7) * 32 + (e >> 3)];

#pragma unroll
    for (int mm = 0; mm < 8; mm++) {
        v2f acc = {0.f, 0.f};
#pragma unroll
        for (int i = 0; i < 16; i++)
            acc = pk_fma(a0[i], *(const v2f*)&P0w[hb * 256 + mm * 32 + 2 * i], acc);
        float vq = acc.x + acc.y;
        vq *= __builtin_amdgcn_rcpf(sigw[hb * 8 + mm]);
        vwt[c * 256 + jl * 8 + mm] = vq;
    }
}

// ---- Kernel 2: block = 4 waves = 8 matrices (8 c of one bt). grid 4096.
// LDS: one 33.8KB buffer; staging dead after column load -> P0/nrm/sig/OUT
// alias into it. __launch_bounds__(256,4): VGPR cap 128 (col+prt+a0 ~112).
__global__ __launch_bounds__(256, 4)
void svd_main_kernel(const float* __restrict__ x, const float* __restrict__ uwd,
                     const float* __restrict__ vwt, float* __restrict__ out) {
    __shared__ float A[8448];     // staging: [mi*1056 + wj*33 + h]

    const int t = threadIdx.x, widx = t >> 6, lane = t & 63;
    const int jl = lane & 31, hb = lane >> 5;
    const int bt = blockIdx.x & 1023, cg = blockIdx.x >> 10;
    const int mi = widx * 2 + hb, c = cg * 8 + mi;

    const float4* x4 = (const float4*)x;
    const size_t cellbase = (size_t)bt * 8192;
    const int c4 = cg * 2;
#pragma unroll
    for (int k2 = 0; k2 < 4; k2++) {
        int idx = t + 256 * k2;              // idx = h*32 + wj
        float4 v0 = x4[cellbase + (size_t)idx * 8 + c4];
        float4 v1 = x4[cellbase + (size_t)idx * 8 + c4 + 1];
        int wj = idx & 31, h = idx >> 5;
        int o = wj * 33 + h;
        A[o]        = v0.x; A[1056 + o] = v0.y; A[2112 + o] = v0.z; A[3168 + o] = v0.w;
        A[4224 + o] = v1.x; A[5280 + o] = v1.y; A[6336 + o] = v1.z; A[7392 + o] = v1.w;
    }
    __syncthreads();

    v2f col[16], a0[16];
    const int cb = mi * 1056 + jl * 33;
#pragma unroll
    for (int i = 0; i < 16; i++) {
        col[i].x = A[cb + 2 * i];
        col[i].y = A[cb + 2 * i + 1];
        a0[i] = col[i];
    }
    __syncthreads();    // ALL waves done reading staging; A is reusable

    float* P0  = A;            // [mi*256 + mm*32 + h]  (2048)
    float* nrm = A + 2048;     // [mi*32 + j]           (256)
    float* sig = A + 2304;     // [mi*8 + mm]           (64)
    float* OUT = A + 2368;     // [mi*512 + l]          (4096, half-pass)

    jacobi2(col, lane, NSWEEP_X);
    rank_pack2(col, jl, P0 + mi * 256, nrm + mi * 32, sig + mi * 8);

    // qv[mm] = (A0^T a_mm / sigma^2) * vw   (lane jl = V-row index w)
    const float* vw = vwt + c * 256;
    const float* uw = uwd + c * 256;
    float qv[8];
#pragma unroll
    for (int mm = 0; mm < 8; mm++) {
        v2f acc = {0.f, 0.f};
#pragma unroll
        for (int i = 0; i < 16; i++)
            acc = pk_fma(a0[i], *(const v2f*)&P0[mi * 256 + mm * 32 + 2 * i], acc);
        float vq = acc.x + acc.y;
        vq *= __builtin_amdgcn_rcpf(sig[mi * 8 + mm]);
        qv[mm] = vq * vw[jl * 8 + mm];
    }

    // Pg in place: P0[mm*32+h] *= uw[h*8+mm]
    for (int e = jl; e < 256; e += 32)
        P0[mi * 256 + e] *= uw[(e & 31) * 8 + (e >> 5)];
    wavefence();

    // out[h][jl] = sum_mm Pg[h][mm]*qv[mm], in two 16-row half-passes.
    float4* o4 = (float4*)out;
    for (int p = 0; p < 2; ++p) {
#pragma unroll
        for (int i = 0; i < 16; i++) {
            int h = p * 16 + i;
            float acc = 0.f;
#pragma unroll
            for (int mm = 0; mm < 8; mm++)
                acc = fmaf(P0[mi * 256 + mm * 32 + h], qv[mm], acc);
            OUT[mi * 512 + i * 32 + jl] = acc;
        }
        __syncthreads();
#pragma unroll
        for (int k2 = 0; k2 < 2; k2++) {
            int l = t + 256 * k2;
            int hh = l >> 5, wj = l & 31;
            int h = p * 16 + hh;
            float4 v0 = make_float4(OUT[l], OUT[512 + l], OUT[1024 + l], OUT[1536 + l]);
            float4 v1 = make_float4(OUT[2048 + l], OUT[2560 + l], OUT[3072 + l], OUT[3584 + l]);
            o4[cellbase + (size_t)(h * 32 + wj) * 8 + c4]     = v0;
            o4[cellbase + (size_t)(h * 32 + wj) * 8 + c4 + 1] = v1;
        }
        if (p == 0) __syncthreads();   // gather done before pass-2 rewrite
    }
}

extern "C" void kernel_launch(void* const* d_in, const int* in_sizes, int n_in,
                              void* d_out, int out_size, void* d_ws, size_t ws_size,
                              hipStream_t stream) {
    (void)in_sizes; (void)n_in; (void)out_size; (void)ws_size;
    const float* x = (const float*)d_in[0];
    const float* w = (const float*)d_in[1];
    float* out = (float*)d_out;
    float* uwd = (float*)d_ws;            // [32][32][8]
    float* vwt = uwd + 32 * 256;          // [32][32][8]

    hipLaunchKernelGGL(svd_w_kernel, dim3(16), dim3(64), 0, stream, w, uwd, vwt);
    hipLaunchKernelGGL(svd_main_kernel, dim3(4096), dim3(256), 0, stream, x, uwd, vwt, out);
}